// Round 4
// baseline (52.124 us; speedup 1.0000x reference)
//
#include <hip/hip_runtime.h>

// TT layer == block-diagonal 8x8 transform:
//   out[b, p*8+m] = sum_j x[b, p*8+j] * M[j][m] + bias[(p%512)*8+m]
// M = A0(8x24)@A1(24x24)@A2(24x24)@A3(24x8), slices of cores_arr (flat reinterprets).
// R4: M held in 16 f32x4 VGPRs (no LDS reads in the hot loop), bias hoisted
// (grid stride 524288 % 512 == 0 so (p&511) is per-thread invariant), k-loop
// hardcoded to 8 iters and unrolled x4 for deep memory-level parallelism.

typedef float f32x4 __attribute__((ext_vector_type(4)));

#define TOTAL_THREADS 524288   // 2048 blocks x 256
#define NBLOCKS       4194304  // out_size / 8
#define ITERS         8        // NBLOCKS / TOTAL_THREADS

__global__ void __launch_bounds__(256) tt_fused(const float* __restrict__ x,
                                                const float* __restrict__ cores,
                                                const float* __restrict__ bias,
                                                float* __restrict__ out) {
    __shared__ float c[1536];
    __shared__ float T1[192];
    __shared__ float T2[192];
    __shared__ __align__(16) float Ms[64];
    const int t = threadIdx.x;
    for (int i = t; i < 1536; i += 256) c[i] = cores[i];
    __syncthreads();
    const float* A0 = c + 1344;  // (8,24)
    const float* A1 = c + 768;   // (24,24)
    const float* A2 = c + 192;   // (24,24)
    const float* A3 = c + 0;     // (24,8)
    if (t < 192) {               // T1 = A0 @ A1  (8x24)
        int r = t / 24, k = t % 24;
        float s = 0.f;
        #pragma unroll
        for (int j = 0; j < 24; ++j) s = fmaf(A0[r * 24 + j], A1[j * 24 + k], s);
        T1[t] = s;
    }
    __syncthreads();
    if (t < 192) {               // T2 = T1 @ A2  (8x24)
        int r = t / 24, k = t % 24;
        float s = 0.f;
        #pragma unroll
        for (int j = 0; j < 24; ++j) s = fmaf(T1[r * 24 + j], A2[j * 24 + k], s);
        T2[t] = s;
    }
    __syncthreads();
    if (t < 64) {                // M = T2 @ A3   (8x8)
        int r = t / 8, m = t % 8;
        float s = 0.f;
        #pragma unroll
        for (int j = 0; j < 24; ++j) s = fmaf(T2[r * 24 + j], A3[j * 8 + m], s);
        Ms[t] = s;
    }
    __syncthreads();

    // M row j lives in Mr[2j] (cols 0-3) and Mr[2j+1] (cols 4-7) — registers.
    f32x4 Mr[16];
    #pragma unroll
    for (int i = 0; i < 16; ++i) Mr[i] = *reinterpret_cast<const f32x4*>(&Ms[i * 4]);

    const int tid = blockIdx.x * 256 + threadIdx.x;

    // bias offset is invariant across grid-stride iterations for this thread
    const int col = (tid & 511) * 8;
    const f32x4 bb0 = *reinterpret_cast<const f32x4*>(bias + col);
    const f32x4 bb1 = *reinterpret_cast<const f32x4*>(bias + col + 4);

    #pragma unroll 4
    for (int k = 0; k < ITERS; ++k) {
        const size_t p = (size_t)tid + (size_t)k * TOTAL_THREADS;
        const f32x4* xp = reinterpret_cast<const f32x4*>(x + p * 8);
        const f32x4 a = xp[0];
        const f32x4 b = xp[1];

        f32x4 acc0 = bb0;
        f32x4 acc1 = bb1;
        const float xv[8] = {a.x, a.y, a.z, a.w, b.x, b.y, b.z, b.w};
        #pragma unroll
        for (int j = 0; j < 8; ++j) {
            acc0 += xv[j] * Mr[2 * j];
            acc1 += xv[j] * Mr[2 * j + 1];
        }

        f32x4* op = reinterpret_cast<f32x4*>(out + p * 8);
        __builtin_nontemporal_store(acc0, op);
        __builtin_nontemporal_store(acc1, op + 1);
    }
}

extern "C" void kernel_launch(void* const* d_in, const int* in_sizes, int n_in,
                              void* d_out, int out_size, void* d_ws, size_t ws_size,
                              hipStream_t stream) {
    const float* x     = (const float*)d_in[0];  // (8192, 4096) fp32
    const float* cores = (const float*)d_in[1];  // (1536,) fp32
    const float* bias  = (const float*)d_in[2];  // (4096,) fp32
    float* out = (float*)d_out;                  // 33554432 fp32

    tt_fused<<<2048, 256, 0, stream>>>(x, cores, bias, out);
}

// Round 5
// 49.316 us; speedup vs baseline: 1.0569x; 1.0569x over previous
//
#include <hip/hip_runtime.h>

// TT layer == block-diagonal 8x8 transform:
//   out[b, p*8+m] = sum_j x[b, p*8+j] * M[j][m] + bias[(p%512)*8+m]
// M = A0(8x24)@A1(24x24)@A2(24x24)@A3(24x8), slices of cores_arr.
// R5: half-block-per-lane layout. Lane g loads ONE f32x4 at x+4g (fully
// contiguous 16B/lane, identical to the 6.3TB/s copy ubench), computes its
// 4 rows' partial against M, swaps partials with its pair lane via shfl_xor(1),
// stores 16B contiguous. Plain stores (nt caused ~8% write amplification, R3/R4).

typedef float f32x4 __attribute__((ext_vector_type(4)));

#define TOTAL_THREADS 524288   // 2048 blocks x 256
#define NHALF         8388608  // out_size / 4 (half-blocks)
#define ITERS         16       // NHALF / TOTAL_THREADS; stride in blocks = 262144 % 512 == 0

__global__ void __launch_bounds__(256) tt_fused(const float* __restrict__ x,
                                                const float* __restrict__ cores,
                                                const float* __restrict__ bias,
                                                float* __restrict__ out) {
    __shared__ float c[1536];
    __shared__ float T1[192];
    __shared__ float T2[192];
    __shared__ __align__(16) float Ms[64];
    const int t = threadIdx.x;
    for (int i = t; i < 1536; i += 256) c[i] = cores[i];
    __syncthreads();
    const float* A0 = c + 1344;  // (8,24)
    const float* A1 = c + 768;   // (24,24)
    const float* A2 = c + 192;   // (24,24)
    const float* A3 = c + 0;     // (24,8)
    if (t < 192) {               // T1 = A0 @ A1  (8x24)
        int r = t / 24, k = t % 24;
        float s = 0.f;
        #pragma unroll
        for (int j = 0; j < 24; ++j) s = fmaf(A0[r * 24 + j], A1[j * 24 + k], s);
        T1[t] = s;
    }
    __syncthreads();
    if (t < 192) {               // T2 = T1 @ A2  (8x24)
        int r = t / 24, k = t % 24;
        float s = 0.f;
        #pragma unroll
        for (int j = 0; j < 24; ++j) s = fmaf(T1[r * 24 + j], A2[j * 24 + k], s);
        T2[t] = s;
    }
    __syncthreads();
    if (t < 64) {                // M = T2 @ A3   (8x8)
        int r = t / 8, m = t % 8;
        float s = 0.f;
        #pragma unroll
        for (int j = 0; j < 24; ++j) s = fmaf(T2[r * 24 + j], A3[j * 8 + m], s);
        Ms[t] = s;
    }
    __syncthreads();

    const int gid = blockIdx.x * 256 + threadIdx.x;
    const int h = gid & 1;  // 0: rows 0-3 / store cols 0-3; 1: rows 4-7 / cols 4-7

    // This lane's 4 rows of M (rows 4h..4h+3), as col-pairs: Msel[2r]=cols0-3, Msel[2r+1]=cols4-7
    f32x4 Msel[8];
    {
        const f32x4* Mb = reinterpret_cast<const f32x4*>(&Ms[h * 32]);
        #pragma unroll
        for (int i = 0; i < 8; ++i) Msel[i] = Mb[i];
    }

    // bias: lane writes out floats [4g .. 4g+3]; column base = 4*(gid & 1023), invariant.
    const f32x4 bb = *reinterpret_cast<const f32x4*>(bias + 4 * (gid & 1023));

    #pragma unroll 4
    for (int k = 0; k < ITERS; ++k) {
        const size_t g = (size_t)gid + (size_t)k * TOTAL_THREADS;
        const f32x4 v = *reinterpret_cast<const f32x4*>(x + g * 4);

        // partials over this lane's 4 rows, all 8 output cols
        f32x4 P0 = v.x * Msel[0] + v.y * Msel[2] + v.z * Msel[4] + v.w * Msel[6];  // cols 0-3
        f32x4 P1 = v.x * Msel[1] + v.y * Msel[3] + v.z * Msel[5] + v.w * Msel[7];  // cols 4-7

        // exchange: partner needs the half I don't store
        f32x4 S = h ? P0 : P1;
        f32x4 R;
        R.x = __shfl_xor(S.x, 1);
        R.y = __shfl_xor(S.y, 1);
        R.z = __shfl_xor(S.z, 1);
        R.w = __shfl_xor(S.w, 1);

        const f32x4 res = (h ? P1 : P0) + R + bb;
        *reinterpret_cast<f32x4*>(out + g * 4) = res;
    }
}

extern "C" void kernel_launch(void* const* d_in, const int* in_sizes, int n_in,
                              void* d_out, int out_size, void* d_ws, size_t ws_size,
                              hipStream_t stream) {
    const float* x     = (const float*)d_in[0];  // (8192, 4096) fp32
    const float* cores = (const float*)d_in[1];  // (1536,) fp32
    const float* bias  = (const float*)d_in[2];  // (4096,) fp32
    float* out = (float*)d_out;                  // 33554432 fp32

    tt_fused<<<2048, 256, 0, stream>>>(x, cores, bias, out);
}